// Round 3
// baseline (803.146 us; speedup 1.0000x reference)
//
#include <hip/hip_runtime.h>

constexpr int B  = 32;
constexpr int C  = 3072;
constexpr int HW = 784;
constexpr int K  = 11;
constexpr int NC = 200;

// d_out layout (floats), concatenated in reference return order
constexpr int AFM_OFF    = 0;         // B*C*K  = 1081344
constexpr int SCORES_OFF = 1081344;   // B*NC   = 6400
constexpr int MAPS_OFF   = 1087744;   // B*K*HW = 275968
constexpr int ATTN_OFF   = 1363712;   // B*K    = 352

// ws layout (floats)
constexpr int WT_OFF   = 0;        // C*12 : w_land transposed, scaled by 2
constexpr int ASQ_OFF  = 36864;    // 16   : a_sq[k]
constexpr int FSUM_OFF = 36880;    // B*C  : modulated sum over k of afm
constexpr int PART_OFF = 135184;   // B*16*K*784 : partial logits
constexpr int PSTRIDE  = K * HW;   // 8624 floats per (b,cc) partial

// ---------------------------------------------------------------- K0: prep
// blocks 0..10: a_sq[k]; blocks 11..22: wT[c][k] = 2*w[k][c]; block 23: zero attn
__global__ __launch_bounds__(256) void k0_prep(const float* __restrict__ w_land,
                                               float* __restrict__ ws,
                                               float* __restrict__ attn) {
  const int bid = blockIdx.x;
  const int t = threadIdx.x;
  if (bid < K) {
    const int k = bid;
    float s = 0.f;
    for (int c = t; c < C; c += 256) {
      float v = w_land[k * C + c];
      s = fmaf(v, v, s);
    }
    __shared__ float red[256];
    red[t] = s;
    __syncthreads();
    for (int off = 128; off > 0; off >>= 1) {
      if (t < off) red[t] += red[t + off];
      __syncthreads();
    }
    if (t == 0) ws[ASQ_OFF + k] = red[0];
  } else if (bid < K + C / 256) {
    const int c = (bid - K) * 256 + t;
    #pragma unroll
    for (int k = 0; k < K; k++)
      ws[WT_OFF + c * 12 + k] = 2.f * w_land[k * C + c];
    ws[WT_OFF + c * 12 + K] = 0.f;
  } else {
    for (int i = t; i < B * K; i += 256) attn[i] = 0.f;
  }
}

// ---------------------------------------------------------------- K1a: partial logits
// grid = B*16 blocks x 512 threads. Block (b, cc) streams its 192-channel slab
// (602 KB) fully sequentially. Thread t owns hw positions {t, 512+t (t<272)};
// accumulates partial logits over K in registers; writes one partial buffer.
__global__ __launch_bounds__(512) void k1a_part(const float* __restrict__ x,
                                                const float* __restrict__ ws,
                                                float* __restrict__ part) {
  const int bid = blockIdx.x;
  const int b   = bid >> 4;
  const int cc  = bid & 15;
  const int c0  = cc * 192;
  const int t   = threadIdx.x;
  const bool pred = t < (HW - 512);  // 272

  const float* xs = x + ((size_t)b * C + c0) * HW;
  const float* wp = ws + WT_OFF + c0 * 12;

  float a0[K], a1[K];
  #pragma unroll
  for (int k = 0; k < K; k++) { a0[k] = 0.f; a1[k] = 0.f; }

  #pragma unroll 2
  for (int c = 0; c < 192; c++) {
    float v0 = xs[(size_t)c * HW + t];
    float v1 = pred ? xs[(size_t)c * HW + 512 + t] : 0.f;
    #pragma unroll
    for (int k = 0; k < K; k++) {
      float wv = wp[c * 12 + k];           // uniform -> s_load
      a0[k] = fmaf(wv, v0, a0[k]);
      a1[k] = fmaf(wv, v1, a1[k]);
    }
  }

  float* pp = part + (size_t)(b * 16 + cc) * PSTRIDE;
  #pragma unroll
  for (int k = 0; k < K; k++) {
    pp[k * HW + t] = a0[k];
    if (pred) pp[k * HW + 512 + t] = a1[k];
  }
}

// ---------------------------------------------------------------- K1b: softmax + attn
// grid = B*13 blocks x 64 threads; lane owns one hw position. Sums 16 partials
// (L2/L3-hot), subtracts a_sq, softmax over K, writes maps + attn.
__global__ __launch_bounds__(64) void k1b_soft(const float* __restrict__ part,
                                               const float* __restrict__ ws,
                                               float* __restrict__ maps_out,
                                               float* __restrict__ attn_out) {
  const int bid  = blockIdx.x;
  const int b    = bid / 13;
  const int tile = bid % 13;
  const int lane = threadIdx.x;
  const int hw   = tile * 64 + lane;
  const bool valid = hw < HW;

  const float* asq = ws + ASQ_OFF;
  const float* pb  = part + (size_t)b * 16 * PSTRIDE;

  float l[K];
  #pragma unroll
  for (int k = 0; k < K; k++) l[k] = -asq[k];
  for (int cc = 0; cc < 16; cc++) {
    #pragma unroll
    for (int k = 0; k < K; k++)
      l[k] += pb[cc * PSTRIDE + k * HW + hw];  // OOB lanes read finite garbage, discarded
  }

  float m = l[0];
  #pragma unroll
  for (int k = 1; k < K; k++) m = fmaxf(m, l[k]);
  float z = 0.f;
  #pragma unroll
  for (int k = 0; k < K; k++) { l[k] = __expf(l[k] - m); z += l[k]; }
  const float inv = 1.f / z;
  #pragma unroll
  for (int k = 0; k < K; k++) {
    float r = l[k] * inv;
    if (valid) maps_out[((size_t)b * K + k) * HW + hw] = r;
    float v = valid ? r : 0.f;
    #pragma unroll
    for (int sh = 32; sh > 0; sh >>= 1) v += __shfl_xor(v, sh);
    if (lane == 0) atomicAdd(&attn_out[b * K + k], v);
  }
}

// ---------------------------------------------------------------- K2: all_features
// grid = B*8 blocks x 512 threads, 105 KB dynamic LDS. Block (b, cc) streams its
// 384-channel slab (1.2 MB) sequentially, 16 rows per chunk into LDS. Wave w
// owns 2 channels/chunk: float4 dots vs LDS maps, 64-lane butterfly reduce,
// results staged in LDS, coalesced modulated epilogue + fsum.
constexpr int XST = 836;             // x row stride (floats), 16B-aligned rows
constexpr int MST = 788;             // maps row stride
constexpr int XC_FLOATS = 16 * XST;      // 13376
constexpr int MS_FLOATS = K * MST;       // 8668
constexpr int FS_FLOATS = 384 * K;       // 4224
constexpr int K2_LDS_BYTES = (XC_FLOATS + MS_FLOATS + FS_FLOATS) * 4;  // 105072

__global__ __launch_bounds__(512) void k2_feat(const float* __restrict__ x,
                                               const float* __restrict__ maps_g,
                                               const float* __restrict__ modulation,
                                               float* __restrict__ afm_out,
                                               float* __restrict__ fsum) {
  extern __shared__ float smem[];
  float* xc     = smem;                       // [16][XST]
  float* maps_s = smem + XC_FLOATS;           // [K][MST]
  float* f_s    = smem + XC_FLOATS + MS_FLOATS;  // [384*K]

  const int bid = blockIdx.x;
  const int b   = (B - 1) - (bid >> 3);       // reverse b: catch K1's L3 tail
  const int c0  = (bid & 7) * 384;
  const int t   = threadIdx.x;
  const int w   = t >> 6;
  const int lane = t & 63;

  for (int k = 0; k < K; k++)
    for (int i = t; i < HW; i += 512)
      maps_s[k * MST + i] = maps_g[((size_t)b * K + k) * HW + i];

  const float* xb = x + ((size_t)b * C + c0) * HW;
  const int cA = 2 * w, cB = 2 * w + 1;
  const bool pred = t < (HW - 512);

  for (int ch = 0; ch < 24; ch++) {
    __syncthreads();
    const float* xrow = xb + (size_t)ch * 16 * HW;
    #pragma unroll
    for (int r = 0; r < 16; r++) {
      float v0 = xrow[(size_t)r * HW + t];
      xc[r * XST + t] = v0;
      if (pred) xc[r * XST + 512 + t] = xrow[(size_t)r * HW + 512 + t];
    }
    __syncthreads();

    float a0[K], a1[K];
    #pragma unroll
    for (int k = 0; k < K; k++) { a0[k] = 0.f; a1[k] = 0.f; }

    const float* xr0 = xc + cA * XST;
    const float* xr1 = xc + cB * XST;
    #pragma unroll
    for (int g = 0; g < 3; g++) {
      const int off = g * 256 + lane * 4;
      const float4 x0 = *(const float4*)(xr0 + off);
      const float4 x1 = *(const float4*)(xr1 + off);
      #pragma unroll
      for (int k = 0; k < K; k++) {
        const float4 m4 = *(const float4*)(maps_s + k * MST + off);
        a0[k] += x0.x * m4.x + x0.y * m4.y + x0.z * m4.z + x0.w * m4.w;
        a1[k] += x1.x * m4.x + x1.y * m4.y + x1.z * m4.z + x1.w * m4.w;
      }
    }
    if (lane < 16) {                      // tail positions 768..783
      const int off = 768 + lane;
      const float x0 = xr0[off], x1 = xr1[off];
      #pragma unroll
      for (int k = 0; k < K; k++) {
        const float ms = maps_s[k * MST + off];
        a0[k] = fmaf(x0, ms, a0[k]);
        a1[k] = fmaf(x1, ms, a1[k]);
      }
    }

    #pragma unroll
    for (int k = 0; k < K; k++) {
      #pragma unroll
      for (int sh = 32; sh > 0; sh >>= 1) {
        a0[k] += __shfl_xor(a0[k], sh);
        a1[k] += __shfl_xor(a1[k], sh);
      }
    }
    if (lane == 0) {
      #pragma unroll
      for (int k = 0; k < K; k++) {
        f_s[(ch * 16 + cA) * K + k] = a0[k];
        f_s[(ch * 16 + cB) * K + k] = a1[k];
      }
    }
  }
  __syncthreads();

  const float inv_hw = 1.f / (float)HW;
  for (int o = t; o < 384 * K; o += 512) {
    float s = f_s[o] * inv_hw * modulation[c0 * K + o];
    afm_out[(size_t)b * C * K + c0 * K + o] = s;
  }
  if (t < 384) {
    float s = 0.f;
    #pragma unroll
    for (int k = 0; k < K; k++)
      s += f_s[t * K + k] * modulation[(c0 + t) * K + k];
    fsum[(size_t)b * C + c0 + t] = s * inv_hw;
  }
}

// ---------------------------------------------------------------- K4: scores
__global__ __launch_bounds__(256) void k4_scores(const float* __restrict__ fsum,
                                                 const float* __restrict__ w_cls,
                                                 float* __restrict__ scores) {
  __shared__ float fs[C];  // 12 KB
  const int bid = blockIdx.x;
  const int b   = bid / (NC / 8);
  const int nt  = bid % (NC / 8);
  const int t   = threadIdx.x;

  for (int i = t; i < C; i += 256) fs[i] = fsum[b * C + i];
  __syncthreads();

  const int nl = t >> 5, lane = t & 31;
  const int n = nt * 8 + nl;
  const float* wr = w_cls + (size_t)n * C;
  float acc = 0.f;
  for (int c = lane; c < C; c += 32) acc = fmaf(wr[c], fs[c], acc);
  #pragma unroll
  for (int sh = 16; sh > 0; sh >>= 1) acc += __shfl_xor(acc, sh);
  if (lane == 0) scores[b * NC + n] = acc;
}

// ----------------------------------------------------------------
extern "C" void kernel_launch(void* const* d_in, const int* in_sizes, int n_in,
                              void* d_out, int out_size, void* d_ws, size_t ws_size,
                              hipStream_t stream) {
  const float* x          = (const float*)d_in[0];
  const float* w_land     = (const float*)d_in[1];
  const float* modulation = (const float*)d_in[2];
  const float* w_cls      = (const float*)d_in[3];

  float* out    = (float*)d_out;
  float* afm    = out + AFM_OFF;
  float* scores = out + SCORES_OFF;
  float* maps   = out + MAPS_OFF;
  float* attn   = out + ATTN_OFF;
  float* ws     = (float*)d_ws;
  float* part   = ws + PART_OFF;

  static bool attr_set = false;
  if (!attr_set) {
    hipFuncSetAttribute((const void*)k2_feat,
                        hipFuncAttributeMaxDynamicSharedMemorySize, K2_LDS_BYTES);
    attr_set = true;
  }

  k0_prep  <<<K + C / 256 + 1, 256, 0, stream>>>(w_land, ws, attn);
  k1a_part <<<B * 16,          512, 0, stream>>>(x, ws, part);
  k1b_soft <<<B * 13,          64,  0, stream>>>(part, ws, maps, attn);
  k2_feat  <<<B * 8,           512, K2_LDS_BYTES, stream>>>(x, maps, modulation, afm, ws + FSUM_OFF);
  k4_scores<<<B * (NC / 8),    256, 0, stream>>>(ws + FSUM_OFF, w_cls, scores);
}